// Round 1
// baseline (651.099 us; speedup 1.0000x reference)
//
#include <hip/hip_runtime.h>
#include <math.h>

// Problem: B=1024, S=512, D=200, A=100
//   uit = tanh(x@W + b)  [B,S,A]
//   ait = exp(uit @ u);  ait /= (sum_s ait + 1e-7)
//   out[b,d] = sum_s x[b,s,d]*ait[b,s]
//
// Design: 1 block (256 thr) per batch. Single pass over x (420MB, the HBM floor):
//   out = (sum_s e_s * x_s) / (sum_s e_s + EPS)   -- no pre-normalization needed.
// Per 64-row chunk: stage x fp32 -> LDS, fp16 MFMA 16x16x32 for xW (K pad 224,
// N pad 128), tanh/dot-u epilogue + shuffle reduce -> e_s, pool from same LDS.
// W converted to fp16, transposed+padded into d_ws by a prep kernel; each wave
// holds its 14 B-fragments in VGPRs for the whole kernel.

typedef _Float16 half8 __attribute__((ext_vector_type(8)));
typedef float float4_ __attribute__((ext_vector_type(4)));

#define B_   1024
#define S_   512
#define D_   200
#define A_   100
#define NPAD 128
#define KPAD 224
#define SC   64     // s-chunk rows
#define PITCH 228   // x_lds row pitch (floats); 228%32==4 -> breaks bank aliasing

#define WT_BYTES (NPAD * KPAD * 2)  // fp16 W^T [NPAD][KPAD]

__global__ void prep_kernel(const float* __restrict__ W,
                            const float* __restrict__ bias,
                            const float* __restrict__ u,
                            void* __restrict__ ws) {
  _Float16* wt = (_Float16*)ws;
  float* upad = (float*)((char*)ws + WT_BYTES);
  float* bpad = upad + NPAD;
  int idx = blockIdx.x * 256 + threadIdx.x;
  if (idx < NPAD * KPAD) {
    int n = idx / KPAD;
    int k = idx % KPAD;
    float v = (n < A_ && k < D_) ? W[k * A_ + n] : 0.f;
    wt[idx] = (_Float16)v;
  }
  if (blockIdx.x == 0 && threadIdx.x < NPAD) {
    int t = threadIdx.x;
    upad[t] = (t < A_) ? u[t] : 0.f;
    bpad[t] = (t < A_) ? bias[t] : 0.f;
  }
}

__global__ __launch_bounds__(256, 2)
void attn_kernel(const float* __restrict__ x,
                 const void* __restrict__ ws,
                 float* __restrict__ out) {
  __shared__ float xs[SC * PITCH];       // 58368 B fp32 x tile (2 blocks/CU fits 160K)
  __shared__ float score_part[4][SC];
  __shared__ float e_lds[SC];

  const int b    = blockIdx.x;
  const int tid  = threadIdx.x;
  const int lane = tid & 63;
  const int wave = tid >> 6;
  const int lm   = lane & 15;   // MFMA col-within-tile
  const int lq   = lane >> 4;   // MFMA quad

  const _Float16* wt = (const _Float16*)ws;
  const float* upad = (const float*)((const char*)ws + WT_BYTES);
  const float* bpad = upad + NPAD;

  // ---- Preload W B-fragments (persistent in VGPRs). Wave w owns n-tiles {2w,2w+1}.
  // B-frag layout (16x16x32): element B[k = lq*8+j][n = lm] of the k-step tile.
  half8 Bfrag[2][7];
  float ureg[2], breg[2];
#pragma unroll
  for (int nn = 0; nn < 2; ++nn) {
    int a = (2 * wave + nn) * 16 + lm;
#pragma unroll
    for (int k = 0; k < 7; ++k) {
      Bfrag[nn][k] = *(const half8*)(wt + (size_t)a * KPAD + k * 32 + lq * 8);
    }
    ureg[nn] = upad[a];
    breg[nn] = bpad[a];
  }

  float acc_out = 0.f, den = 0.f;

  for (int chunk = 0; chunk < S_ / SC; ++chunk) {
    __syncthreads();  // previous pooling must finish before restaging xs

    // ---- Stage x[b, chunk*64 : +64, :] -> LDS fp32, zero-pad cols 200..227.
    // lane c = float4 slot (50 real + 7 pad), wave covers rows wave+4j.
    {
      int c  = tid & 63;
      int r0 = tid >> 6;
      const float* xg = x + ((size_t)b * S_ + (size_t)chunk * SC) * D_;
#pragma unroll
      for (int j = 0; j < 16; ++j) {
        int row = r0 + 4 * j;
        if (c < 50) {
          float4_ v = *(const float4_*)(xg + row * D_ + c * 4);
          *(float4_*)(&xs[row * PITCH + c * 4]) = v;
        } else if (c < 57) {
          float4_ z = {0.f, 0.f, 0.f, 0.f};
          *(float4_*)(&xs[row * PITCH + c * 4]) = z;
        }
      }
    }
    __syncthreads();

    // ---- MFMA: uit-chunk = x_chunk @ W. Every wave does all 4 m-tiles x its 2 n-tiles.
    float4_ acc[4][2];
#pragma unroll
    for (int m = 0; m < 4; ++m)
#pragma unroll
      for (int nn = 0; nn < 2; ++nn)
        acc[m][nn] = (float4_){0.f, 0.f, 0.f, 0.f};

#pragma unroll
    for (int k = 0; k < 7; ++k) {
      half8 af[4];
#pragma unroll
      for (int m = 0; m < 4; ++m) {
        int row = m * 16 + lm;
        int col = k * 32 + lq * 8;
        float4_ lo = *(const float4_*)(&xs[row * PITCH + col]);
        float4_ hi = *(const float4_*)(&xs[row * PITCH + col + 4]);
        half8 a;
        a[0] = (_Float16)lo.x; a[1] = (_Float16)lo.y;
        a[2] = (_Float16)lo.z; a[3] = (_Float16)lo.w;
        a[4] = (_Float16)hi.x; a[5] = (_Float16)hi.y;
        a[6] = (_Float16)hi.z; a[7] = (_Float16)hi.w;
        af[m] = a;
      }
#pragma unroll
      for (int m = 0; m < 4; ++m)
#pragma unroll
        for (int nn = 0; nn < 2; ++nn)
          acc[m][nn] = __builtin_amdgcn_mfma_f32_16x16x32_f16(
              af[m], Bfrag[nn][k], acc[m][nn], 0, 0, 0);
    }

    // ---- Epilogue: t = tanh(c + b[a]) * u[a]; reduce over a.
    // C/D layout: col(a) = lm, row(s_local) = m*16 + lq*4 + r.
    float p[4][4];
#pragma unroll
    for (int m = 0; m < 4; ++m) {
#pragma unroll
      for (int r = 0; r < 4; ++r) {
        float s0 = 0.f;
#pragma unroll
        for (int nn = 0; nn < 2; ++nn) {
          float z  = acc[m][nn][r] + breg[nn];
          float az = fabsf(z);
          float ez = __expf(az + az);               // e^{2|z|}; overflow->inf is fine
          float rc = __builtin_amdgcn_rcpf(ez + 1.f);
          float t  = fmaf(-2.f, rc, 1.f);           // tanh(|z|)
          t = copysignf(t, z);
          s0 = fmaf(t, ureg[nn], s0);
        }
        p[m][r] = s0;
      }
    }
    // sum over the 16 cols (lanes sharing lane>>4 group)
#pragma unroll
    for (int m = 0; m < 4; ++m) {
#pragma unroll
      for (int r = 0; r < 4; ++r) {
        float v = p[m][r];
        v += __shfl_xor(v, 1);
        v += __shfl_xor(v, 2);
        v += __shfl_xor(v, 4);
        v += __shfl_xor(v, 8);
        p[m][r] = v;
      }
    }
    if (lm == 0) {
#pragma unroll
      for (int m = 0; m < 4; ++m)
#pragma unroll
        for (int r = 0; r < 4; ++r)
          score_part[wave][m * 16 + lq * 4 + r] = p[m][r];
    }
    __syncthreads();

    if (tid < SC) {
      float ssum = score_part[0][tid] + score_part[1][tid] +
                   score_part[2][tid] + score_part[3][tid];
      e_lds[tid] = __expf(ssum);   // faithful: no max-subtraction (matches reference)
    }
    __syncthreads();

    // ---- Pool: acc_out[d] += e_s * x[s][d]; den += e_s. Thread tid owns column d=tid.
    if (tid < D_) {
#pragma unroll 4
      for (int s = 0; s < SC; ++s) {
        float e = e_lds[s];
        den += e;
        acc_out = fmaf(e, xs[s * PITCH + tid], acc_out);
      }
    }
  }

  if (tid < D_) {
    out[(size_t)b * D_ + tid] = acc_out / (den + 1e-7f);
  }
}

extern "C" void kernel_launch(void* const* d_in, const int* in_sizes, int n_in,
                              void* d_out, int out_size, void* d_ws, size_t ws_size,
                              hipStream_t stream) {
  const float* x = (const float*)d_in[0];
  const float* W = (const float*)d_in[1];
  const float* b = (const float*)d_in[2];
  const float* u = (const float*)d_in[3];
  float* out = (float*)d_out;

  // prep: fp16 W^T padded [128][224] + padded u/b into ws (ws re-poisoned each
  // launch, so this must run every call — it does).
  int prep_elems = NPAD * KPAD;
  int prep_blocks = (prep_elems + 255) / 256;
  prep_kernel<<<prep_blocks, 256, 0, stream>>>(W, b, u, d_ws);

  attn_kernel<<<B_, 256, 0, stream>>>(x, d_ws, out);
}

// Round 2
// 589.557 us; speedup vs baseline: 1.1044x; 1.1044x over previous
//
#include <hip/hip_runtime.h>
#include <math.h>

// Problem: B=1024, S=512, D=200, A=100
//   uit = tanh(x@W + b); ait = exp(uit@u); ait /= (sum_s ait + EPS)
//   out[b,d] = sum_s x[b,s,d]*ait[b,s]
//
// R2 design: softmax num/den are both plain sums over s, so split S across
// blocks: 8192 blocks (b x 8 chunks of 64 rows), each fully independent:
//   stage x-chunk fp32->fp16 into LDS (~30KB -> 4-5 blocks/CU, cvt out of
//   the MFMA loop), fp16 MFMA 16x16x32 (K pad 224, N pad 128), tanh/dot-u
//   epilogue, partial pool -> ws. Reduce kernel combines 8 partials + divides.
// x touches HBM exactly once (420MB -> ~70us floor).

typedef _Float16 half8 __attribute__((ext_vector_type(8)));
typedef _Float16 half4_ __attribute__((ext_vector_type(4)));
typedef float float4_ __attribute__((ext_vector_type(4)));

#define B_   1024
#define S_   512
#define D_   200
#define A_   100
#define NPAD 128
#define KPAD 224
#define SC   64          // s-rows per block
#define NCH  (S_ / SC)   // 8 chunks per batch
#define PITCH_H 232      // fp16 LDS pitch: 464B rows, 16B-aligned, 2-way bank alias (free)

#define WT_BYTES (NPAD * KPAD * 2)          // fp16 W^T [NPAD][KPAD]
#define UB_BYTES (NPAD * 2 * 4)             // upad + bpad
#define NUM_OFF  (WT_BYTES + UB_BYTES)      // float num[8192][200]
#define DEN_OFF  (NUM_OFF + (size_t)B_ * NCH * D_ * 4)  // float den[8192]

__global__ void prep_kernel(const float* __restrict__ W,
                            const float* __restrict__ bias,
                            const float* __restrict__ u,
                            void* __restrict__ ws) {
  _Float16* wt = (_Float16*)ws;
  float* upad = (float*)((char*)ws + WT_BYTES);
  float* bpad = upad + NPAD;
  int idx = blockIdx.x * 256 + threadIdx.x;
  if (idx < NPAD * KPAD) {
    int n = idx / KPAD;
    int k = idx % KPAD;
    float v = (n < A_ && k < D_) ? W[k * A_ + n] : 0.f;
    wt[idx] = (_Float16)v;
  }
  if (blockIdx.x == 0 && threadIdx.x < NPAD) {
    int t = threadIdx.x;
    upad[t] = (t < A_) ? u[t] : 0.f;
    bpad[t] = (t < A_) ? bias[t] : 0.f;
  }
}

__global__ __launch_bounds__(256, 4)
void attn_kernel(const float* __restrict__ x,
                 void* __restrict__ ws) {
  __shared__ _Float16 xs[SC * PITCH_H];   // 29696 B
  __shared__ float score_part[4][SC];
  __shared__ float e_lds[SC];

  const int blk  = blockIdx.x;            // b*8 + chunk
  const int b    = blk >> 3;
  const int chunk= blk & 7;
  const int tid  = threadIdx.x;
  const int lane = tid & 63;
  const int wave = tid >> 6;
  const int lm   = lane & 15;
  const int lq   = lane >> 4;

  const _Float16* wt = (const _Float16*)ws;
  const float* upad = (const float*)((const char*)ws + WT_BYTES);
  const float* bpad = upad + NPAD;
  float* num_out = (float*)((char*)ws + NUM_OFF);
  float* den_out = (float*)((char*)ws + DEN_OFF);

  // ---- Preload W B-fragments: wave w owns n-tiles {2w, 2w+1}.
  half8 Bfrag[2][7];
  float ureg[2], breg[2];
#pragma unroll
  for (int nn = 0; nn < 2; ++nn) {
    int a = (2 * wave + nn) * 16 + lm;
#pragma unroll
    for (int k = 0; k < 7; ++k)
      Bfrag[nn][k] = *(const half8*)(wt + (size_t)a * KPAD + k * 32 + lq * 8);
    ureg[nn] = upad[a];
    breg[nn] = bpad[a];
  }

  // ---- Stage x[b, chunk*64 : +64, :] -> LDS fp16, zero-pad cols 200..223.
  {
    int c  = tid & 63;     // float4 slot
    int r0 = tid >> 6;
    const float* xg = x + ((size_t)b * S_ + (size_t)chunk * SC) * D_;
#pragma unroll
    for (int j = 0; j < 16; ++j) {
      int row = r0 + 4 * j;
      if (c < 50) {
        float4_ v = *(const float4_*)(xg + row * D_ + c * 4);
        half4_ h = {(_Float16)v.x, (_Float16)v.y, (_Float16)v.z, (_Float16)v.w};
        *(half4_*)(&xs[row * PITCH_H + c * 4]) = h;
      } else if (c < 56) {
        half4_ z = {(_Float16)0.f, (_Float16)0.f, (_Float16)0.f, (_Float16)0.f};
        *(half4_*)(&xs[row * PITCH_H + c * 4]) = z;
      }
    }
  }
  __syncthreads();

  // ---- MFMA: uit-chunk = x_chunk @ W (64 x 128, K=224).
  float4_ acc[4][2];
#pragma unroll
  for (int m = 0; m < 4; ++m)
#pragma unroll
    for (int nn = 0; nn < 2; ++nn)
      acc[m][nn] = (float4_){0.f, 0.f, 0.f, 0.f};

#pragma unroll
  for (int k = 0; k < 7; ++k) {
    half8 af[4];
#pragma unroll
    for (int m = 0; m < 4; ++m)
      af[m] = *(const half8*)(&xs[(m * 16 + lm) * PITCH_H + k * 32 + lq * 8]);
#pragma unroll
    for (int m = 0; m < 4; ++m)
#pragma unroll
      for (int nn = 0; nn < 2; ++nn)
        acc[m][nn] = __builtin_amdgcn_mfma_f32_16x16x32_f16(
            af[m], Bfrag[nn][k], acc[m][nn], 0, 0, 0);
  }

  // ---- Epilogue: tanh(c + b[a]) * u[a], reduce over a (cols).
  // C/D layout: col(a)=lm, row(s_local)=m*16+lq*4+r.
  float p[4][4];
#pragma unroll
  for (int m = 0; m < 4; ++m) {
#pragma unroll
    for (int r = 0; r < 4; ++r) {
      float s0 = 0.f;
#pragma unroll
      for (int nn = 0; nn < 2; ++nn) {
        float z  = acc[m][nn][r] + breg[nn];
        float az = fabsf(z);
        float ez = __expf(az + az);
        float rc = __builtin_amdgcn_rcpf(ez + 1.f);
        float t  = fmaf(-2.f, rc, 1.f);
        t = copysignf(t, z);
        s0 = fmaf(t, ureg[nn], s0);
      }
      float v = s0;
      v += __shfl_xor(v, 1);
      v += __shfl_xor(v, 2);
      v += __shfl_xor(v, 4);
      v += __shfl_xor(v, 8);
      p[m][r] = v;
    }
  }
  if (lm == 0) {
#pragma unroll
    for (int m = 0; m < 4; ++m)
#pragma unroll
      for (int r = 0; r < 4; ++r)
        score_part[wave][m * 16 + lq * 4 + r] = p[m][r];
  }
  __syncthreads();

  // ---- e_s = exp(score) (faithful: no max-subtract); partial denominator.
  if (tid < SC) {
    float ssum = score_part[0][tid] + score_part[1][tid] +
                 score_part[2][tid] + score_part[3][tid];
    float e = __expf(ssum);
    e_lds[tid] = e;
    float d = e;
    d += __shfl_xor(d, 1);
    d += __shfl_xor(d, 2);
    d += __shfl_xor(d, 4);
    d += __shfl_xor(d, 8);
    d += __shfl_xor(d, 16);
    d += __shfl_xor(d, 32);
    if (tid == 0) den_out[blk] = d;
  }
  __syncthreads();

  // ---- Partial pool: num[blk][d] = sum_s e_s * x[s][d].
  if (tid < D_) {
    float accv = 0.f;
#pragma unroll 4
    for (int s = 0; s < SC; ++s)
      accv = fmaf(e_lds[s], (float)xs[s * PITCH_H + tid], accv);
    num_out[(size_t)blk * D_ + tid] = accv;
  }
}

__global__ __launch_bounds__(256)
void reduce_kernel(const void* __restrict__ ws, float* __restrict__ out) {
  const float* num = (const float*)((const char*)ws + NUM_OFF);
  const float* den = (const float*)((const char*)ws + DEN_OFF);
  int b = blockIdx.x;
  int tid = threadIdx.x;
  if (tid < D_) {
    float s = 0.f, d = 0.f;
#pragma unroll
    for (int c = 0; c < NCH; ++c) {
      s += num[(size_t)(b * NCH + c) * D_ + tid];
      d += den[b * NCH + c];
    }
    out[(size_t)b * D_ + tid] = s / (d + 1e-7f);
  }
}

extern "C" void kernel_launch(void* const* d_in, const int* in_sizes, int n_in,
                              void* d_out, int out_size, void* d_ws, size_t ws_size,
                              hipStream_t stream) {
  const float* x = (const float*)d_in[0];
  const float* W = (const float*)d_in[1];
  const float* b = (const float*)d_in[2];
  const float* u = (const float*)d_in[3];
  float* out = (float*)d_out;

  int prep_elems = NPAD * KPAD;
  int prep_blocks = (prep_elems + 255) / 256;
  prep_kernel<<<prep_blocks, 256, 0, stream>>>(W, b, u, d_ws);
  attn_kernel<<<B_ * NCH, 256, 0, stream>>>(x, d_ws);
  reduce_kernel<<<B_, 256, 0, stream>>>(d_ws, out);
}

// Round 3
// 587.727 us; speedup vs baseline: 1.1078x; 1.0031x over previous
//
#include <hip/hip_runtime.h>
#include <math.h>

// Problem: B=1024, S=512, D=200, A=100
//   uit = tanh(x@W + b); ait = exp(uit@u); ait /= (sum_s ait + EPS)
//   out[b,d] = sum_s x[b,s,d]*ait[b,s]
//
// R3: same 8192-block split-S structure as R2; cut LDS-pipe pressure so the
// kernel is HBM-bound:
//  - 16-lane score reduction via DPP row_shr (VALU) instead of __shfl_xor
//    (LDS swizzle pipe): ~1550 cyc/block saved.
//  - pool vectorized: per-wave 16-s slice, ds_read_b64 (half4) instead of 256
//    scalar ds_read_u16: ~1000 cyc/block saved. Per-wave partial numerators;
//    reduce kernel sums 32 partials per batch.

typedef _Float16 half8 __attribute__((ext_vector_type(8)));
typedef _Float16 half4_ __attribute__((ext_vector_type(4)));
typedef float float4_ __attribute__((ext_vector_type(4)));

#define B_   1024
#define S_   512
#define D_   200
#define A_   100
#define NPAD 128
#define KPAD 224
#define SC   64          // s-rows per block
#define NCH  (S_ / SC)   // 8 chunks per batch
#define PITCH_H 232      // fp16 LDS pitch (232 halves = 464B; 2-way bank alias only)

#define WT_BYTES (NPAD * KPAD * 2)
#define UB_BYTES (NPAD * 2 * 4)
#define NUM_OFF  (WT_BYTES + UB_BYTES)                      // float num[8192][4][200]
#define DEN_OFF  (NUM_OFF + (size_t)B_ * NCH * 4 * D_ * 4)  // float den[8192]

// DPP row_shr add: after 1,2,4,8 steps, lane 15 of each 16-lane row holds the
// row sum (bound_ctrl=1 zero-fills shifted-in lanes).
#define DPP_ADD(v, ctrl)                                                     \
  v += __builtin_bit_cast(float, __builtin_amdgcn_update_dpp(                \
           0, __builtin_bit_cast(int, v), (ctrl), 0xF, 0xF, true))

__global__ void prep_kernel(const float* __restrict__ W,
                            const float* __restrict__ bias,
                            const float* __restrict__ u,
                            void* __restrict__ ws) {
  _Float16* wt = (_Float16*)ws;
  float* upad = (float*)((char*)ws + WT_BYTES);
  float* bpad = upad + NPAD;
  int idx = blockIdx.x * 256 + threadIdx.x;
  if (idx < NPAD * KPAD) {
    int n = idx / KPAD;
    int k = idx % KPAD;
    float v = (n < A_ && k < D_) ? W[k * A_ + n] : 0.f;
    wt[idx] = (_Float16)v;
  }
  if (blockIdx.x == 0 && threadIdx.x < NPAD) {
    int t = threadIdx.x;
    upad[t] = (t < A_) ? u[t] : 0.f;
    bpad[t] = (t < A_) ? bias[t] : 0.f;
  }
}

__global__ __launch_bounds__(256, 4)
void attn_kernel(const float* __restrict__ x,
                 void* __restrict__ ws) {
  __shared__ _Float16 xs[SC * PITCH_H];   // 29696 B
  __shared__ float score_part[4][SC];
  __shared__ float e_lds[SC];

  const int blk  = blockIdx.x;            // b*8 + chunk
  const int b    = blk >> 3;
  const int chunk= blk & 7;
  const int tid  = threadIdx.x;
  const int lane = tid & 63;
  const int wave = tid >> 6;
  const int lm   = lane & 15;
  const int lq   = lane >> 4;

  const _Float16* wt = (const _Float16*)ws;
  const float* upad = (const float*)((const char*)ws + WT_BYTES);
  const float* bpad = upad + NPAD;
  float* num_out = (float*)((char*)ws + NUM_OFF);
  float* den_out = (float*)((char*)ws + DEN_OFF);

  // ---- Preload W B-fragments: wave w owns n-tiles {2w, 2w+1}.
  half8 Bfrag[2][7];
  float ureg[2], breg[2];
#pragma unroll
  for (int nn = 0; nn < 2; ++nn) {
    int a = (2 * wave + nn) * 16 + lm;
#pragma unroll
    for (int k = 0; k < 7; ++k)
      Bfrag[nn][k] = *(const half8*)(wt + (size_t)a * KPAD + k * 32 + lq * 8);
    ureg[nn] = upad[a];
    breg[nn] = bpad[a];
  }

  // ---- Stage x[b, chunk*64 : +64, :] -> LDS fp16, zero-pad cols 200..223.
  {
    int c  = tid & 63;     // float4 slot
    int r0 = tid >> 6;
    const float* xg = x + ((size_t)b * S_ + (size_t)chunk * SC) * D_;
#pragma unroll
    for (int j = 0; j < 16; ++j) {
      int row = r0 + 4 * j;
      if (c < 50) {
        float4_ v = *(const float4_*)(xg + row * D_ + c * 4);
        half4_ h = {(_Float16)v.x, (_Float16)v.y, (_Float16)v.z, (_Float16)v.w};
        *(half4_*)(&xs[row * PITCH_H + c * 4]) = h;
      } else if (c < 56) {
        half4_ z = {(_Float16)0.f, (_Float16)0.f, (_Float16)0.f, (_Float16)0.f};
        *(half4_*)(&xs[row * PITCH_H + c * 4]) = z;
      }
    }
  }
  __syncthreads();

  // ---- MFMA: uit-chunk = x_chunk @ W (64 x 128, K=224).
  float4_ acc[4][2];
#pragma unroll
  for (int m = 0; m < 4; ++m)
#pragma unroll
    for (int nn = 0; nn < 2; ++nn)
      acc[m][nn] = (float4_){0.f, 0.f, 0.f, 0.f};

#pragma unroll
  for (int k = 0; k < 7; ++k) {
#pragma unroll
    for (int m = 0; m < 4; ++m) {
      half8 af = *(const half8*)(&xs[(m * 16 + lm) * PITCH_H + k * 32 + lq * 8]);
#pragma unroll
      for (int nn = 0; nn < 2; ++nn)
        acc[m][nn] = __builtin_amdgcn_mfma_f32_16x16x32_f16(
            af, Bfrag[nn][k], acc[m][nn], 0, 0, 0);
    }
  }

  // ---- Epilogue: tanh(c + b[a]) * u[a]; DPP row-reduce over the 16 cols.
  // C/D layout: col(a)=lm, row(s_local)=m*16+lq*4+r. Lane lm==15 holds sums.
#pragma unroll
  for (int m = 0; m < 4; ++m) {
#pragma unroll
    for (int r = 0; r < 4; ++r) {
      float v = 0.f;
#pragma unroll
      for (int nn = 0; nn < 2; ++nn) {
        float z  = acc[m][nn][r] + breg[nn];
        float az = fabsf(z);
        float ez = __expf(az + az);
        float rc = __builtin_amdgcn_rcpf(ez + 1.f);
        float t  = fmaf(-2.f, rc, 1.f);
        t = copysignf(t, z);
        v = fmaf(t, ureg[nn], v);
      }
      DPP_ADD(v, 0x111);  // row_shr:1
      DPP_ADD(v, 0x112);  // row_shr:2
      DPP_ADD(v, 0x114);  // row_shr:4
      DPP_ADD(v, 0x118);  // row_shr:8 -> lane 15 of each row has the sum
      if (lm == 15) score_part[wave][m * 16 + lq * 4 + r] = v;
    }
  }
  __syncthreads();

  // ---- e_s = exp(score) (faithful: no max-subtract); block denominator.
  if (tid < SC) {
    float ssum = score_part[0][tid] + score_part[1][tid] +
                 score_part[2][tid] + score_part[3][tid];
    float e = __expf(ssum);
    e_lds[tid] = e;
    float d = e;
    d += __shfl_xor(d, 1);
    d += __shfl_xor(d, 2);
    d += __shfl_xor(d, 4);
    d += __shfl_xor(d, 8);
    d += __shfl_xor(d, 16);
    d += __shfl_xor(d, 32);
    if (tid == 0) den_out[blk] = d;
  }
  __syncthreads();

  // ---- Pool: wave w covers s in [16w, 16w+16); lanes 0..49 own 4 d-cols.
  if (lane < 50) {
    float4_ accv = {0.f, 0.f, 0.f, 0.f};
#pragma unroll
    for (int i = 0; i < 16; ++i) {
      int s = wave * 16 + i;
      float e = e_lds[s];
      half4_ h = *(const half4_*)(&xs[s * PITCH_H + lane * 4]);
      accv.x = fmaf(e, (float)h.x, accv.x);
      accv.y = fmaf(e, (float)h.y, accv.y);
      accv.z = fmaf(e, (float)h.z, accv.z);
      accv.w = fmaf(e, (float)h.w, accv.w);
    }
    *(float4_*)(&num_out[((size_t)blk * 4 + wave) * D_ + lane * 4]) = accv;
  }
}

__global__ __launch_bounds__(256)
void reduce_kernel(const void* __restrict__ ws, float* __restrict__ out) {
  const float* num = (const float*)((const char*)ws + NUM_OFF);
  const float* den = (const float*)((const char*)ws + DEN_OFF);
  int b = blockIdx.x;
  int tid = threadIdx.x;
  if (tid < D_) {
    float d = 0.f;
#pragma unroll
    for (int c = 0; c < NCH; ++c) d += den[b * NCH + c];
    float s = 0.f;
#pragma unroll
    for (int j = 0; j < NCH * 4; ++j)
      s += num[((size_t)b * NCH * 4 + j) * D_ + tid];
    out[(size_t)b * D_ + tid] = s / (d + 1e-7f);
  }
}

extern "C" void kernel_launch(void* const* d_in, const int* in_sizes, int n_in,
                              void* d_out, int out_size, void* d_ws, size_t ws_size,
                              hipStream_t stream) {
  const float* x = (const float*)d_in[0];
  const float* W = (const float*)d_in[1];
  const float* b = (const float*)d_in[2];
  const float* u = (const float*)d_in[3];
  float* out = (float*)d_out;

  int prep_elems = NPAD * KPAD;
  int prep_blocks = (prep_elems + 255) / 256;
  prep_kernel<<<prep_blocks, 256, 0, stream>>>(W, b, u, d_ws);
  attn_kernel<<<B_ * NCH, 256, 0, stream>>>(x, d_ws);
  reduce_kernel<<<B_, 256, 0, stream>>>(d_ws, out);
}